// Round 11
// baseline (1857.236 us; speedup 1.0000x reference)
//
#include <hip/hip_runtime.h>
#include <hip/hip_fp16.h>
#include <math.h>
#include <stdint.h>

typedef _Float16 f16;
typedef _Float16 h8 __attribute__((ext_vector_type(8)));
typedef float f4 __attribute__((ext_vector_type(4)));

#define TSTEPS 48

#define MFMA(a,b,c) __builtin_amdgcn_mfma_f32_16x16x32_f16((a),(b),(c),0,0,0)

__device__ __forceinline__ float gelu_f(float x) {
  float ax = fabsf(x) * 0.7071067811865475f;
  float t = __builtin_amdgcn_rcpf(1.0f + 0.3275911f * ax);
  float poly = t * (0.254829592f + t * (-0.284496736f + t * (1.421413741f +
               t * (-1.453152027f + t * 1.061405429f))));
  float e = exp2f(-ax * ax * 1.4426950408889634f);
  float er = copysignf(1.0f - poly * e, x);
  return 0.5f * x * (1.0f + er);
}

__device__ __forceinline__ float tanh_f(float x) {
  float e = exp2f(x * 2.885390081777927f);
  return 1.0f - 2.0f * __builtin_amdgcn_rcpf(e + 1.0f);
}

// ---------------- unified lane-linear weight prep ----------------
// Fragment (kk, cf): 16 cols c0=cf*16, 32 k's at kk*32. Lane ln holds 8 f16:
// dst[fragid*512 + ln*8 + e] = src[(kk*32 + (ln>>4)*8 + e) * N + cf*16 + (ln&15)]
__global__ void prep_lin(const float* __restrict__ src, f16* __restrict__ dst,
                         int Kreal, int N, int total) {
  int idx = blockIdx.x * 256 + threadIdx.x;
  if (idx >= total) return;
  int fragid = idx >> 9;
  int within = idx & 511;
  int ln = within >> 3, e = within & 7;
  int nfr = N >> 4;
  int kk = fragid / nfr, cf = fragid - kk * nfr;
  int k = kk * 32 + ((ln >> 4) << 3) + e;
  int n = (cf << 4) + (ln & 15);
  dst[idx] = (f16)((k < Kreal) ? src[k * N + n] : 0.f);
}

// ---------------- feature kernel: fourier + hashgrid + z -> fp16 [B][192] ----
__global__ void feat_kernel(const float* __restrict__ x, const float* __restrict__ z,
                            const float* __restrict__ tables, const int* __restrict__ res,
                            const float* __restrict__ freqs, f16* __restrict__ featsH) {
  __shared__ f16 rowbuf[64][194];
  const int t = threadIdx.x;        // 64 threads
  const int b = blockIdx.x;
  const int i = b * 64 + t;

  float xv = x[i];
  float xn = fminf(fmaxf(xv, 0.f), 1.f);
  f16* dst = rowbuf[t];
  dst[0] = (f16)xn;
  float w2pi = 6.283185307179586f * xn;
  #pragma unroll
  for (int k = 0; k < 32; ++k) {
    float a = w2pi * freqs[k];
    float s, c;
    sincosf(a, &s, &c);
    dst[1 + k]  = (f16)s;
    dst[33 + k] = (f16)c;
  }
  #pragma unroll
  for (int l = 0; l < 8; ++l) {
    int R = res[l];
    int Rm1 = R - 1;
    float tt = xn * (float)Rm1;
    int i0 = (int)tt;
    int i1 = min(i0 + 1, Rm1);
    float w = tt - (float)i0;
    uint32_t lt = (uint32_t)(l * 19349663);
    uint32_t h0 = (((uint32_t)i0 * 73856093u) ^ lt) & 16383u;
    uint32_t h1 = (((uint32_t)i1 * 73856093u) ^ lt) & 16383u;
    const float* e0 = tables + ((size_t)l * 16384 + h0) * 8;
    const float* e1 = tables + ((size_t)l * 16384 + h1) * 8;
    #pragma unroll
    for (int e = 0; e < 8; ++e) {
      float v = e0[e] * (1.f - w) + e1[e] * w;
      dst[65 + l * 8 + e] = (f16)v;
    }
  }
  #pragma unroll
  for (int j = 0; j < 32; ++j) dst[129 + j] = (f16)z[(size_t)i * 32 + j];
  #pragma unroll
  for (int j = 161; j < 192; ++j) dst[j] = (f16)0.f;

  __syncthreads();
  uint32_t* dg = (uint32_t*)(featsH + (size_t)b * 64 * 192);
  for (int idx = t; idx < 64 * 96; idx += 64) {
    int row = idx / 96, o = idx - row * 96;
    dg[idx] = ((const uint32_t*)&rowbuf[row][0])[o];
  }
}

// ---------------- main fused kernel ----------------
// 256 blocks x 1024 threads (16 waves), 1 block/CU, 4 waves/SIMD.
// SPILL-FREE BY CONSTRUCTION: the allocator splits the unified reg file
// ~half arch / half acc (R3-R10 evidence: reported VGPR always = cap/2).
// Arch demand here ~55 (a[4]=16, bb[2]=8, addr ~15, biases 6, misc ~10);
// acc 32 in AGPR half. Master h lives in LDS (mB, f32) - epilogue-only use.
// No prefetch rings: 4 waves/SIMD TLP hides L2 latency.
// LDS 160KB exactly: hB 32K (h f16 [64][256], swz), uB 64K (u f16 [64][512],
// swz; feats staging reuses), mB 64K (m f32 [64][256], swz).
// Scratch traffic = 0 -> per-XCD L2 keeps the 512KB weight stream resident.
__global__ __launch_bounds__(1024)
__attribute__((amdgpu_waves_per_eu(4, 4)))
void fractal_main(
    const f16* __restrict__ featsH,
    const f16* __restrict__ W1L, const f16* __restrict__ W2L,
    const f16* __restrict__ WoL,
    const f16* __restrict__ Wf1L, const f16* __restrict__ Wf2L,
    const float* __restrict__ b1, const float* __restrict__ b2,
    const float* __restrict__ bf1, const float* __restrict__ bf2,
    const float* __restrict__ bo,
    float* __restrict__ out) {
  extern __shared__ char smem[];
  char* hB = smem;             // 32KB
  char* uB = smem + 32768;     // 64KB
  char* mB = smem + 98304;     // 64KB (f32 master h)

  const int tid = threadIdx.x;
  const int wn  = tid >> 6;          // 0..15
  const int ln  = tid & 63;
  const int r   = ln & 15;
  const int g   = ln >> 4;
  const int sw  = (r & 7) << 4;
  const int g16 = g * 16;
  const int row0 = blockIdx.x * 64;

  const int cH = 16 * wn + r;        // wave's HID-space column
  float b1r = b1[cH], b2r = b2[cH], bf2r = bf2[cH], bor = bo[cH];
  float bf1r[2];
  #pragma unroll
  for (int nf = 0; nf < 2; ++nf) bf1r[nf] = bf1[32 * wn + 16 * nf + r];

  // per-wave lane-linear stream bases
  const f16* w1p  = W1L  + (size_t)wn * 512 + ln * 8;       // frag kk*16+wn
  const f16* w2p  = W2L  + (size_t)wn * 512 + ln * 8;
  const f16* wop  = WoL  + (size_t)wn * 512 + ln * 8;
  const f16* wf1p = Wf1L + (size_t)(2 * wn) * 512 + ln * 8; // frag kk*32+2wn+nf
  const f16* wf2p = Wf2L + (size_t)wn * 512 + ln * 8;       // frag kk*16+wn

  // ---- stage feats tile into uB (swizzled, row stride 384B) ----
  {
    const char* src = (const char*)featsH + (size_t)row0 * 384;
    for (int i = tid; i < 6144; i += 1024) {
      int row = i / 96;
      int off = (i - row * 96) * 4;
      uint32_t v = *(const uint32_t*)(src + (size_t)i * 4);
      *(uint32_t*)(uB + row * 384 + (off ^ ((row & 7) << 4))) = v;
    }
  }
  __syncthreads();

  const f4 zf = {0.f, 0.f, 0.f, 0.f};

  // ---- layer 1: h1 = gelu(feats @ W1 + b1) -> hB ----
  {
    f4 acc[4];
    #pragma unroll
    for (int mf = 0; mf < 4; ++mf) acc[mf] = zf;
    #pragma unroll
    for (int kk = 0; kk < 6; ++kk) {
      h8 bb = *(const h8*)(w1p + ((size_t)(kk * 16) << 9));
      #pragma unroll
      for (int mf = 0; mf < 4; ++mf) {
        h8 a = *(const h8*)(uB + (16 * mf + r) * 384 + ((kk * 64 + g16) ^ sw));
        acc[mf] = MFMA(a, bb, acc[mf]);
      }
    }
    #pragma unroll
    for (int mf = 0; mf < 4; ++mf)
      #pragma unroll
      for (int j = 0; j < 4; ++j) {
        float hv = gelu_f(acc[mf][j] + b1r);
        int row = 16 * mf + g * 4 + j;
        *(f16*)(hB + row * 512 + ((cH * 2) ^ ((row & 7) << 4))) = (f16)hv;
      }
  }
  __syncthreads();

  // ---- layer 2: h0 = gelu(h1 @ W2 + b2) -> hB + mB ----
  {
    f4 acc[4];
    #pragma unroll
    for (int mf = 0; mf < 4; ++mf) acc[mf] = zf;
    #pragma unroll
    for (int kk = 0; kk < 8; ++kk) {
      h8 bb = *(const h8*)(w2p + ((size_t)(kk * 16) << 9));
      #pragma unroll
      for (int mf = 0; mf < 4; ++mf) {
        h8 a = *(const h8*)(hB + (16 * mf + r) * 512 + ((kk * 64 + g16) ^ sw));
        acc[mf] = MFMA(a, bb, acc[mf]);
      }
    }
    __syncthreads();   // done reading h1 before overwriting hB
    #pragma unroll
    for (int mf = 0; mf < 4; ++mf)
      #pragma unroll
      for (int j = 0; j < 4; ++j) {
        float hv = gelu_f(acc[mf][j] + b2r);
        int row = 16 * mf + g * 4 + j;
        *(f16*)(hB + row * 512 + ((cH * 2) ^ ((row & 7) << 4))) = (f16)hv;
        *(float*)(mB + row * 1024 + ((cH * 4) ^ ((row & 7) << 4))) = hv;
      }
  }
  __syncthreads();

  // ---- 48 fractal steps, 2 barriers per step ----
  #pragma unroll 1
  for (int t = 0; t < TSTEPS; ++t) {
    // GEMM1: u = gelu(h @ Wf1 + bf1), wave cols [32wn,+32)
    f4 a1[4][2];
    #pragma unroll
    for (int mf = 0; mf < 4; ++mf)
      #pragma unroll
      for (int nf = 0; nf < 2; ++nf) a1[mf][nf] = zf;
    #pragma unroll
    for (int kk = 0; kk < 8; ++kk) {
      h8 bb0 = *(const h8*)(wf1p + ((size_t)(kk * 32) << 9));
      h8 bb1 = *(const h8*)(wf1p + ((size_t)(kk * 32 + 1) << 9));
      #pragma unroll
      for (int mf = 0; mf < 4; ++mf) {
        h8 a = *(const h8*)(hB + (16 * mf + r) * 512 + ((kk * 64 + g16) ^ sw));
        a1[mf][0] = MFMA(a, bb0, a1[mf][0]);
        a1[mf][1] = MFMA(a, bb1, a1[mf][1]);
      }
    }
    #pragma unroll
    for (int mf = 0; mf < 4; ++mf)
      #pragma unroll
      for (int nf = 0; nf < 2; ++nf)
        #pragma unroll
        for (int j = 0; j < 4; ++j) {
          float gv = gelu_f(a1[mf][nf][j] + bf1r[nf]);
          int row = 16 * mf + g * 4 + j;
          int col = 32 * wn + 16 * nf + r;
          *(f16*)(uB + row * 1024 + ((col * 2) ^ ((row & 7) << 4))) = (f16)gv;
        }
    __syncthreads();

    // GEMM2: h' = 0.5*(m + tanh(u @ Wf2 + bf2)), wave cols [16wn,+16)
    f4 a2[4];
    #pragma unroll
    for (int mf = 0; mf < 4; ++mf) a2[mf] = zf;
    #pragma unroll
    for (int kk = 0; kk < 16; ++kk) {
      h8 bb = *(const h8*)(wf2p + ((size_t)(kk * 16) << 9));
      #pragma unroll
      for (int mf = 0; mf < 4; ++mf) {
        h8 a = *(const h8*)(uB + (16 * mf + r) * 1024 + ((kk * 64 + g16) ^ sw));
        a2[mf] = MFMA(a, bb, a2[mf]);
      }
    }
    #pragma unroll
    for (int mf = 0; mf < 4; ++mf)
      #pragma unroll
      for (int j = 0; j < 4; ++j) {
        int row = 16 * mf + g * 4 + j;
        float* mp = (float*)(mB + row * 1024 + ((cH * 4) ^ ((row & 7) << 4)));
        float u = tanh_f(a2[mf][j] + bf2r);
        float hn = 0.5f * (*mp + u);
        *mp = hn;
        *(f16*)(hB + row * 512 + ((cH * 2) ^ ((row & 7) << 4))) = (f16)hn;
      }
    __syncthreads();
  }

  // ---- final: out = h @ Wo + bo ----
  {
    f4 acc[4];
    #pragma unroll
    for (int mf = 0; mf < 4; ++mf) acc[mf] = zf;
    #pragma unroll
    for (int kk = 0; kk < 8; ++kk) {
      h8 bb = *(const h8*)(wop + ((size_t)(kk * 16) << 9));
      #pragma unroll
      for (int mf = 0; mf < 4; ++mf) {
        h8 a = *(const h8*)(hB + (16 * mf + r) * 512 + ((kk * 64 + g16) ^ sw));
        acc[mf] = MFMA(a, bb, acc[mf]);
      }
    }
    #pragma unroll
    for (int mf = 0; mf < 4; ++mf)
      #pragma unroll
      for (int j = 0; j < 4; ++j) {
        int row = row0 + 16 * mf + g * 4 + j;
        out[(size_t)row * 256 + cH] = acc[mf][j] + bor;
      }
  }
}

// ---------------- host launch ----------------
extern "C" void kernel_launch(void* const* d_in, const int* in_sizes, int n_in,
                              void* d_out, int out_size, void* d_ws, size_t ws_size,
                              hipStream_t stream) {
  const float* x      = (const float*)d_in[0];
  const float* z      = (const float*)d_in[1];
  const float* tables = (const float*)d_in[2];
  const float* W1     = (const float*)d_in[3];
  const float* b1     = (const float*)d_in[4];
  const float* W2     = (const float*)d_in[5];
  const float* b2     = (const float*)d_in[6];
  const float* Wf1    = (const float*)d_in[7];
  const float* bf1    = (const float*)d_in[8];
  const float* Wf2    = (const float*)d_in[9];
  const float* bf2    = (const float*)d_in[10];
  const float* Wo     = (const float*)d_in[11];
  const float* bo     = (const float*)d_in[12];
  const int*   res    = (const int*)d_in[13];
  const float* freqs  = (const float*)d_in[14];
  float* out = (float*)d_out;

  char* ws = (char*)d_ws;
  f16* featsH = (f16*)(ws);                 // 16384*192*2 = 6291456
  f16* W1L    = (f16*)(ws + 6291456);       // 96 frags  * 1KB = 98304
  f16* W2L    = (f16*)(ws + 6389760);       // 128 frags * 1KB = 131072
  f16* WoL    = (f16*)(ws + 6520832);       // 131072
  f16* Wf1L   = (f16*)(ws + 6651904);       // 256 frags * 1KB = 262144
  f16* Wf2L   = (f16*)(ws + 6914048);       // 262144

  prep_lin<<<192, 256, 0, stream>>>(W1,  W1L,  161, 256, 96  * 512);
  prep_lin<<<256, 256, 0, stream>>>(W2,  W2L,  256, 256, 128 * 512);
  prep_lin<<<256, 256, 0, stream>>>(Wo,  WoL,  256, 256, 128 * 512);
  prep_lin<<<512, 256, 0, stream>>>(Wf1, Wf1L, 256, 512, 256 * 512);
  prep_lin<<<512, 256, 0, stream>>>(Wf2, Wf2L, 512, 256, 256 * 512);
  feat_kernel<<<256, 64, 0, stream>>>(x, z, tables, res, freqs, featsH);

  (void)hipFuncSetAttribute((const void*)fractal_main,
                            hipFuncAttributeMaxDynamicSharedMemorySize, 163840);
  fractal_main<<<256, 1024, 163840, stream>>>(featsH, W1L, W2L, WoL, Wf1L, Wf2L,
                                              b1, b2, bf1, bf2, bo, out);
}